// Round 1
// baseline (108.632 us; speedup 1.0000x reference)
//
#include <hip/hip_runtime.h>

#define BB 8
#define HH 256
#define WW 256
#define NROWS (BB * HH)            // 2048
#define NTOT (BB * HH * WW)        // 524288

// ---------------- Kernel 1: vertical EDT pass (per column) ----------------
// One thread per (batch, column). Forward scan writes running distance into
// g2 buffer; backward scan takes min, squares, writes g^2. Empty columns get
// a sentinel (1e9) which can never win the horizontal min in a nonempty
// image (see analysis: nonempty candidate <= 130050 < 263169 = 513^2).
__global__ __launch_bounds__(WW) void edt_vertical(
    const float* __restrict__ target, float* __restrict__ g2,
    int* __restrict__ flags) {
  const int b = blockIdx.x;   // 0..7
  const int j = threadIdx.x;  // 0..255 column
  const int base = b * (HH * WW) + j;

  float d = 512.0f;
  bool any = false;
  for (int i = 0; i < HH; ++i) {
    const bool fg = target[base + i * WW] > 0.5f;
    any |= fg;
    d = fg ? 0.0f : d + 1.0f;
    g2[base + i * WW] = d;
  }
  d = 512.0f;
  for (int i = HH - 1; i >= 0; --i) {
    const bool fg = target[base + i * WW] > 0.5f;
    d = fg ? 0.0f : d + 1.0f;
    const float g = fminf(g2[base + i * WW], d);
    g2[base + i * WW] = any ? g * g : 1.0e9f;
  }
  if (any) atomicOr(&flags[b], 1);
}

// ------- Kernel 2: horizontal EDT (exact min) + fused elementwise/reduce ----
// One block per image row (b*HH + i). Computes dt for the row, plus the five
// reduction quantities, block-reduces in fp32, writes per-block partials.
__global__ __launch_bounds__(WW) void edt_row_and_reduce(
    const float* __restrict__ logits, const float* __restrict__ target,
    const float* __restrict__ g2, const int* __restrict__ flags,
    float* __restrict__ partials /* [5][NROWS] */) {
  __shared__ float s_g2[WW];
  __shared__ float s_red[4 * 5];

  const int row = blockIdx.x;   // b*HH + i
  const int b = row >> 8;
  const int j = threadIdx.x;
  const int rowbase = row * WW;

  s_g2[j] = g2[rowbase + j];
  __syncthreads();

  // exact dt^2 = min_k (j-k)^2 + g2[k]; 4 accumulators for ILP
  const float jf = (float)j;
  float m0 = 3.4e38f, m1 = 3.4e38f, m2 = 3.4e38f, m3 = 3.4e38f;
#pragma unroll 4
  for (int k = 0; k < WW; k += 4) {
    float d0 = jf - (float)(k + 0);
    float d1 = jf - (float)(k + 1);
    float d2 = jf - (float)(k + 2);
    float d3 = jf - (float)(k + 3);
    m0 = fminf(m0, fmaf(d0, d0, s_g2[k + 0]));
    m1 = fminf(m1, fmaf(d1, d1, s_g2[k + 1]));
    m2 = fminf(m2, fmaf(d2, d2, s_g2[k + 2]));
    m3 = fminf(m3, fmaf(d3, d3, s_g2[k + 3]));
  }
  const float m = fminf(fminf(m0, m1), fminf(m2, m3));
  const float dt = flags[b] ? sqrtf(m) : 0.0f;

  // fused elementwise
  const float x = logits[rowbase + j];
  float t = target[rowbase + j];
  t = fminf(fmaxf(t, 0.0f), 1.0f);
  const float ce = fmaxf(x, 0.0f) + log1pf(expf(-fabsf(x))) - x * t;
  float p = 1.0f / (1.0f + expf(-x));
  p = fminf(fmaxf(p, 1e-6f), 1.0f - 1e-6f);

  float v[5];
  v[0] = ce;
  v[1] = p;
  v[2] = t;
  v[3] = p * t;
  v[4] = p * dt;

  // wave(64) shuffle reduce, then cross-wave via LDS
  const int lane = j & 63;
  const int wave = j >> 6;
#pragma unroll
  for (int q = 0; q < 5; ++q) {
    float s = v[q];
#pragma unroll
    for (int off = 32; off > 0; off >>= 1) s += __shfl_down(s, off, 64);
    if (lane == 0) s_red[wave * 5 + q] = s;
  }
  __syncthreads();
  if (j == 0) {
#pragma unroll
    for (int q = 0; q < 5; ++q) {
      const float s = s_red[q] + s_red[5 + q] + s_red[10 + q] + s_red[15 + q];
      partials[q * NROWS + row] = s;
    }
  }
}

// ---------------- Kernel 3: final reduction (double) + loss math -----------
__global__ __launch_bounds__(256) void finalize(
    const float* __restrict__ partials, float* __restrict__ out) {
  __shared__ double s_red[4 * 5];
  const int j = threadIdx.x;  // 256 threads
  double acc[5] = {0.0, 0.0, 0.0, 0.0, 0.0};
  for (int i = j; i < NROWS; i += 256) {
#pragma unroll
    for (int q = 0; q < 5; ++q) acc[q] += (double)partials[q * NROWS + i];
  }
  const int lane = j & 63;
  const int wave = j >> 6;
#pragma unroll
  for (int q = 0; q < 5; ++q) {
    double s = acc[q];
#pragma unroll
    for (int off = 32; off > 0; off >>= 1) s += __shfl_down(s, off, 64);
    if (lane == 0) s_red[wave * 5 + q] = s;
  }
  __syncthreads();
  if (j == 0) {
    double sum[5];
#pragma unroll
    for (int q = 0; q < 5; ++q)
      sum[q] = s_red[q] + s_red[5 + q] + s_red[10 + q] + s_red[15 + q];
    const double n = (double)NTOT;
    const double ce = sum[0] / n;
    const double dice = 1.0 - (2.0 * sum[3] + 1e-6) / (sum[1] + sum[2] + 1e-6);
    const double boundary = sum[4] / n;
    const double total = 1.0 * ce + 1.0 * dice + 0.1 * boundary;
    out[0] = (float)total;
    out[1] = (float)ce;
    out[2] = (float)dice;
    out[3] = (float)boundary;
  }
}

extern "C" void kernel_launch(void* const* d_in, const int* in_sizes, int n_in,
                              void* d_out, int out_size, void* d_ws,
                              size_t ws_size, hipStream_t stream) {
  const float* logits = (const float*)d_in[0];
  const float* target = (const float*)d_in[1];
  float* out = (float*)d_out;

  char* ws = (char*)d_ws;
  int* flags = (int*)ws;                          // 32 B (8 ints)
  float* partials = (float*)(ws + 64);            // 5*2048*4 = 40960 B
  float* g2 = (float*)(ws + 64 + 5 * NROWS * 4);  // NTOT*4 = 2 MB

  hipMemsetAsync(flags, 0, 64, stream);
  edt_vertical<<<BB, WW, 0, stream>>>(target, g2, flags);
  edt_row_and_reduce<<<NROWS, WW, 0, stream>>>(logits, target, g2, flags,
                                               partials);
  finalize<<<1, 256, 0, stream>>>(partials, out);
}

// Round 2
// 77.126 us; speedup vs baseline: 1.4085x; 1.4085x over previous
//
#include <hip/hip_runtime.h>

#define BB 8
#define HH 256
#define WW 256
#define NROWS (BB * HH)            // 2048
#define NTOT (BB * HH * WW)        // 524288

// ---------------- Kernel 1: build per-column foreground bitmasks ----------
// Grid (8 stripes, 8 batches) x 256 threads. Thread = column j; packs 32
// rows (stripe s: rows 32s..32s+31) into one u32. All 32 loads independent
// + coalesced -> latency fully pipelined. Output layout masks[b][s][j]
// (u32), so both this store and the main kernel's loads are coalesced.
__global__ __launch_bounds__(256) void build_masks(
    const float* __restrict__ target, unsigned* __restrict__ masks) {
  const int s = blockIdx.x;  // stripe 0..7 (rows 32s..32s+31)
  const int b = blockIdx.y;  // batch 0..7
  const int j = threadIdx.x; // column
  const float* base = target + b * (HH * WW) + s * 32 * WW + j;
  unsigned m = 0;
#pragma unroll
  for (int r = 0; r < 32; ++r)
    if (base[r * WW] > 0.5f) m |= (1u << r);
  masks[b * 2048 + s * 256 + j] = m;
}

// ------- Kernel 2: vertical EDT from masks + horizontal exact min + fused --
// One block per image row (b*HH + i). Thread j:
//  (a) loads its column's 8 mask words, computes g^2(i,j) = (nearest set
//      bit distance)^2 via ctz/clz (sentinel 1e9 for empty column -- can
//      never win the horizontal min in a nonempty image: 513^2 > 255^2*2),
//  (b) exact dt^2 = min_k (j-k)^2 + g^2(k) brute force over LDS,
//  (c) fused BCE/sigmoid/dice/boundary terms, block-reduced to partials.
__global__ __launch_bounds__(256) void main_kernel(
    const float* __restrict__ logits, const float* __restrict__ target,
    const unsigned* __restrict__ masks,
    float* __restrict__ partials /* [5][NROWS] */) {
  __shared__ float s_g2[WW];
  __shared__ float s_red[4 * 5];
  __shared__ int s_any[4];

  const int row = blockIdx.x;  // b*HH + i
  const int b = row >> 8;
  const int i = row & 255;
  const int j = threadIdx.x;
  const int rowbase = row * WW;
  const int lane = j & 63;
  const int wave = j >> 6;

  // (a) column mask -> vertical distance
  unsigned m[8];
#pragma unroll
  for (int w = 0; w < 8; ++w) m[w] = masks[b * 2048 + w * 256 + j];

  const int wi = i >> 5, r = i & 31;
  int dUp = 1 << 30, dDn = 1 << 30;
  const unsigned cur = m[wi] >> r;  // bits at rows >= i within word
  if (cur) {
    dUp = __builtin_ctz(cur);
  } else {
    int off = 32 - r;
    for (int w2 = wi + 1; w2 < 8; ++w2, off += 32)
      if (m[w2]) { dUp = off + __builtin_ctz(m[w2]); break; }
  }
  const unsigned curd = m[wi] << (31 - r);  // bits at rows <= i, high end
  if (curd) {
    dDn = __builtin_clz(curd);
  } else {
    int off = r + 1;
    for (int w2 = wi - 1; w2 >= 0; --w2, off += 32)
      if (m[w2]) { dDn = off + __builtin_clz(m[w2]); break; }
  }
  const int d = min(dUp, dDn);
  s_g2[j] = (d < 256) ? (float)(d * d) : 1.0e9f;

  const unsigned many = m[0] | m[1] | m[2] | m[3] | m[4] | m[5] | m[6] | m[7];
  const int wave_any = __any(many != 0u);
  if (lane == 0) s_any[wave] = wave_any;
  __syncthreads();
  const int nonempty = s_any[0] | s_any[1] | s_any[2] | s_any[3];

  // (b) exact dt^2 = min_k (j-k)^2 + g2[k]; 4 accumulators for ILP
  const float jf = (float)j;
  float m0 = 3.4e38f, m1 = 3.4e38f, m2 = 3.4e38f, m3 = 3.4e38f;
#pragma unroll 4
  for (int k = 0; k < WW; k += 4) {
    float d0 = jf - (float)(k + 0);
    float d1 = jf - (float)(k + 1);
    float d2 = jf - (float)(k + 2);
    float d3 = jf - (float)(k + 3);
    m0 = fminf(m0, fmaf(d0, d0, s_g2[k + 0]));
    m1 = fminf(m1, fmaf(d1, d1, s_g2[k + 1]));
    m2 = fminf(m2, fmaf(d2, d2, s_g2[k + 2]));
    m3 = fminf(m3, fmaf(d3, d3, s_g2[k + 3]));
  }
  const float mn = fminf(fminf(m0, m1), fminf(m2, m3));
  const float dt = nonempty ? sqrtf(mn) : 0.0f;

  // (c) fused elementwise
  const float x = logits[rowbase + j];
  float t = target[rowbase + j];
  t = fminf(fmaxf(t, 0.0f), 1.0f);
  const float ce = fmaxf(x, 0.0f) + log1pf(expf(-fabsf(x))) - x * t;
  float p = 1.0f / (1.0f + expf(-x));
  p = fminf(fmaxf(p, 1e-6f), 1.0f - 1e-6f);

  float v[5];
  v[0] = ce;
  v[1] = p;
  v[2] = t;
  v[3] = p * t;
  v[4] = p * dt;

#pragma unroll
  for (int q = 0; q < 5; ++q) {
    float s = v[q];
#pragma unroll
    for (int off = 32; off > 0; off >>= 1) s += __shfl_down(s, off, 64);
    if (lane == 0) s_red[wave * 5 + q] = s;
  }
  __syncthreads();
  if (j == 0) {
#pragma unroll
    for (int q = 0; q < 5; ++q) {
      const float s = s_red[q] + s_red[5 + q] + s_red[10 + q] + s_red[15 + q];
      partials[q * NROWS + row] = s;
    }
  }
}

// ---------------- Kernel 3: final reduction (double) + loss math -----------
__global__ __launch_bounds__(256) void finalize(
    const float* __restrict__ partials, float* __restrict__ out) {
  __shared__ double s_red[4 * 5];
  const int j = threadIdx.x;  // 256 threads
  double acc[5] = {0.0, 0.0, 0.0, 0.0, 0.0};
  for (int i = j; i < NROWS; i += 256) {
#pragma unroll
    for (int q = 0; q < 5; ++q) acc[q] += (double)partials[q * NROWS + i];
  }
  const int lane = j & 63;
  const int wave = j >> 6;
#pragma unroll
  for (int q = 0; q < 5; ++q) {
    double s = acc[q];
#pragma unroll
    for (int off = 32; off > 0; off >>= 1) s += __shfl_down(s, off, 64);
    if (lane == 0) s_red[wave * 5 + q] = s;
  }
  __syncthreads();
  if (j == 0) {
    double sum[5];
#pragma unroll
    for (int q = 0; q < 5; ++q)
      sum[q] = s_red[q] + s_red[5 + q] + s_red[10 + q] + s_red[15 + q];
    const double n = (double)NTOT;
    const double ce = sum[0] / n;
    const double dice = 1.0 - (2.0 * sum[3] + 1e-6) / (sum[1] + sum[2] + 1e-6);
    const double boundary = sum[4] / n;
    const double total = 1.0 * ce + 1.0 * dice + 0.1 * boundary;
    out[0] = (float)total;
    out[1] = (float)ce;
    out[2] = (float)dice;
    out[3] = (float)boundary;
  }
}

extern "C" void kernel_launch(void* const* d_in, const int* in_sizes, int n_in,
                              void* d_out, int out_size, void* d_ws,
                              size_t ws_size, hipStream_t stream) {
  const float* logits = (const float*)d_in[0];
  const float* target = (const float*)d_in[1];
  float* out = (float*)d_out;

  char* ws = (char*)d_ws;
  unsigned* masks = (unsigned*)ws;                 // 8*2048*4 = 64 KB
  float* partials = (float*)(ws + 64 * 1024);      // 5*2048*4 = 40 KB

  build_masks<<<dim3(8, 8), 256, 0, stream>>>(target, masks);
  main_kernel<<<NROWS, 256, 0, stream>>>(logits, target, masks, partials);
  finalize<<<1, 256, 0, stream>>>(partials, out);
}

// Round 3
// 69.095 us; speedup vs baseline: 1.5722x; 1.1162x over previous
//
#include <hip/hip_runtime.h>

#define BB 8
#define HH 256
#define WW 256
#define NROWS (BB * HH)            // 2048
#define NTOT (BB * HH * WW)        // 524288

// ---------------- Kernel 1: build per-column foreground bitmasks ----------
__global__ __launch_bounds__(256) void build_masks(
    const float* __restrict__ target, unsigned* __restrict__ masks) {
  const int s = blockIdx.x;  // stripe 0..7 (rows 32s..32s+31)
  const int b = blockIdx.y;  // batch 0..7
  const int j = threadIdx.x; // column
  const float* base = target + b * (HH * WW) + s * 32 * WW + j;
  unsigned m = 0;
#pragma unroll
  for (int r = 0; r < 32; ++r)
    if (base[r * WW] > 0.5f) m |= (1u << r);
  masks[b * 2048 + s * 256 + j] = m;
}

// ------- Kernel 2: vertical EDT from masks + PRUNED horizontal min + fused -
// Exactness of pruning: k=j gives dt2(j) <= g2(j), so any argmin k* has
// |j-k*| <= d_j. Scanning |delta| <= R with R = block_max(min(d_j,255))
// therefore preserves the exact min. Empty column -> d_j clamps to 255 ->
// full scan (correct, slow; probability 2^-256 with this data).
__global__ __launch_bounds__(256) void main_kernel(
    const float* __restrict__ logits, const float* __restrict__ target,
    const unsigned* __restrict__ masks,
    float* __restrict__ partials /* [5][NROWS] */) {
  __shared__ float s_g2[WW];
  __shared__ float s_red[4 * 5];
  __shared__ int s_any[4];
  __shared__ int s_rmax[4];

  const int row = blockIdx.x;  // b*HH + i
  const int b = row >> 8;
  const int i = row & 255;
  const int j = threadIdx.x;
  const int rowbase = row * WW;
  const int lane = j & 63;
  const int wave = j >> 6;

  // (a) column mask -> vertical distance d
  unsigned m[8];
#pragma unroll
  for (int w = 0; w < 8; ++w) m[w] = masks[b * 2048 + w * 256 + j];

  const int wi = i >> 5, r = i & 31;
  int dUp = 1 << 30, dDn = 1 << 30;
  const unsigned cur = m[wi] >> r;  // bits at rows >= i within word
  if (cur) {
    dUp = __builtin_ctz(cur);
  } else {
    int off = 32 - r;
    for (int w2 = wi + 1; w2 < 8; ++w2, off += 32)
      if (m[w2]) { dUp = off + __builtin_ctz(m[w2]); break; }
  }
  const unsigned curd = m[wi] << (31 - r);  // bits at rows <= i, high end
  if (curd) {
    dDn = __builtin_clz(curd);
  } else {
    int off = r + 1;
    for (int w2 = wi - 1; w2 >= 0; --w2, off += 32)
      if (m[w2]) { dDn = off + __builtin_clz(m[w2]); break; }
  }
  const int d = min(dUp, dDn);
  s_g2[j] = (d < 256) ? (float)(d * d) : 1.0e9f;
  const int rj = min(d, 255);

  // wave reductions: image-nonempty flag + max scan radius
  const unsigned many = m[0] | m[1] | m[2] | m[3] | m[4] | m[5] | m[6] | m[7];
  const int wave_any = __any(many != 0u);
  int rmax = rj;
#pragma unroll
  for (int off = 32; off > 0; off >>= 1) rmax = max(rmax, __shfl_down(rmax, off, 64));
  if (lane == 0) { s_any[wave] = wave_any; s_rmax[wave] = rmax; }
  __syncthreads();
  const int nonempty = s_any[0] | s_any[1] | s_any[2] | s_any[3];
  const int R = max(max(s_rmax[0], s_rmax[1]), max(s_rmax[2], s_rmax[3]));

  // (b) pruned exact dt^2 = min_{|delta|<=R} delta^2 + g2[j+delta]
  float mn = 1.0e30f;
  for (int dlt = -R; dlt <= R; ++dlt) {
    const int k = j + dlt;
    if ((unsigned)k < 256u)
      mn = fminf(mn, (float)(dlt * dlt) + s_g2[k]);
  }
  const float dt = nonempty ? sqrtf(mn) : 0.0f;

  // (c) fused elementwise: one exp, one log, one rcp
  const float x = logits[rowbase + j];
  float t = target[rowbase + j];
  t = fminf(fmaxf(t, 0.0f), 1.0f);
  const float e = __expf(-fabsf(x));          // exp(-|x|) in (0,1]
  const float inv = 1.0f / (1.0f + e);
  const float ce = fmaxf(x, 0.0f) + __logf(1.0f + e) - x * t;
  float p = (x >= 0.0f) ? inv : e * inv;      // sigmoid(x)
  p = fminf(fmaxf(p, 1e-6f), 1.0f - 1e-6f);

  float v[5];
  v[0] = ce;
  v[1] = p;
  v[2] = t;
  v[3] = p * t;
  v[4] = p * dt;

#pragma unroll
  for (int q = 0; q < 5; ++q) {
    float s = v[q];
#pragma unroll
    for (int off = 32; off > 0; off >>= 1) s += __shfl_down(s, off, 64);
    if (lane == 0) s_red[wave * 5 + q] = s;
  }
  __syncthreads();
  if (j == 0) {
#pragma unroll
    for (int q = 0; q < 5; ++q) {
      const float s = s_red[q] + s_red[5 + q] + s_red[10 + q] + s_red[15 + q];
      partials[q * NROWS + row] = s;
    }
  }
}

// ---------------- Kernel 3: final reduction (double) + loss math -----------
__global__ __launch_bounds__(256) void finalize(
    const float* __restrict__ partials, float* __restrict__ out) {
  __shared__ double s_red[4 * 5];
  const int j = threadIdx.x;  // 256 threads
  double acc[5] = {0.0, 0.0, 0.0, 0.0, 0.0};
  for (int i = j; i < NROWS; i += 256) {
#pragma unroll
    for (int q = 0; q < 5; ++q) acc[q] += (double)partials[q * NROWS + i];
  }
  const int lane = j & 63;
  const int wave = j >> 6;
#pragma unroll
  for (int q = 0; q < 5; ++q) {
    double s = acc[q];
#pragma unroll
    for (int off = 32; off > 0; off >>= 1) s += __shfl_down(s, off, 64);
    if (lane == 0) s_red[wave * 5 + q] = s;
  }
  __syncthreads();
  if (j == 0) {
    double sum[5];
#pragma unroll
    for (int q = 0; q < 5; ++q)
      sum[q] = s_red[q] + s_red[5 + q] + s_red[10 + q] + s_red[15 + q];
    const double n = (double)NTOT;
    const double ce = sum[0] / n;
    const double dice = 1.0 - (2.0 * sum[3] + 1e-6) / (sum[1] + sum[2] + 1e-6);
    const double boundary = sum[4] / n;
    const double total = 1.0 * ce + 1.0 * dice + 0.1 * boundary;
    out[0] = (float)total;
    out[1] = (float)ce;
    out[2] = (float)dice;
    out[3] = (float)boundary;
  }
}

extern "C" void kernel_launch(void* const* d_in, const int* in_sizes, int n_in,
                              void* d_out, int out_size, void* d_ws,
                              size_t ws_size, hipStream_t stream) {
  const float* logits = (const float*)d_in[0];
  const float* target = (const float*)d_in[1];
  float* out = (float*)d_out;

  char* ws = (char*)d_ws;
  unsigned* masks = (unsigned*)ws;                 // 8*2048*4 = 64 KB
  float* partials = (float*)(ws + 64 * 1024);      // 5*2048*4 = 40 KB

  build_masks<<<dim3(8, 8), 256, 0, stream>>>(target, masks);
  main_kernel<<<NROWS, 256, 0, stream>>>(logits, target, masks, partials);
  finalize<<<1, 256, 0, stream>>>(partials, out);
}